// Round 10
// baseline (184.232 us; speedup 1.0000x reference)
//
#include <hip/hip_runtime.h>
#include <hip/hip_bf16.h>

#define HID   1024
#define H3    3072
#define SEQ   2048
#define NB    4
#define MTOT  8192   // NB*SEQ

typedef __bf16 bf16;
typedef bf16  bf16x4 __attribute__((ext_vector_type(4)));
typedef bf16  bf16x8 __attribute__((ext_vector_type(8)));
typedef float f32x4  __attribute__((ext_vector_type(4)));

#define MFMA16(a, b, c) __builtin_amdgcn_mfma_f32_16x16x32_bf16((a), (b), (c), 0, 0, 0)

#define GLOAD_LDS16(gp, lp)                                                     \
    __builtin_amdgcn_global_load_lds(                                           \
        (const __attribute__((address_space(1))) void*)(gp),                    \
        (__attribute__((address_space(3))) void*)(lp), 16, 0, 0)

#define FENCE() asm volatile("" ::: "memory")

// ===========================================================================
// Staging: 128 rows x 64 cols of bf16 as 16 subtiles (16x32, 1024 B) with
// involutive XOR swizzle (pre-swizzled global source, linear LDS dest).
// ===========================================================================
__device__ __forceinline__ void stage_half(
    const bf16* __restrict__ G, long ld, long row0, long col0,
    char* dstbase, int w, int lane)
{
    const int r  = lane >> 2;
    const int c0 = ((lane & 3) * 8) ^ (((lane >> 5) & 1) << 4);
#pragma unroll
    for (int l = 0; l < 2; ++l) {
        const int sh = l * 8 + w;
        const bf16* src = G + (row0 + (long)((sh >> 1) * 16 + r)) * ld
                            + col0 + ((sh & 1) * 32 + c0);
        GLOAD_LDS16(src, dstbase + sh * 1024);
    }
}

// ===========================================================================
// 256x256 B-DIRECT core: A staged in LDS (dbuf 64 KB), B loaded straight from
// global (L2) into register fragment sets, prefetched one K-tile ahead.
// 4 register half-sets (S0..S3), loop unrolled x2 for static indexing.
// Issue order per tile: Ah0(2), NLo(4), Ah1(2), NHi(4) -> vmcnt(4) at p3
// guarantees A[t+1] landed while NHi still flies.
// ===========================================================================
#define QK_TILE(t, Ac, An, CLo, CHi, NLo, NHi)                                 \
{                                                                              \
    const bool doP = ((t) + 1 < NT);                                           \
    const long kA = (long)((t) + 1) * 64;                                      \
    const long bo = (long)((t) + 1) * 64;                                      \
    /* p0: aR(wave m-lo) + stage A[t+1]h0; MFMA q(lo,lo) */                    \
    _Pragma("unroll") for (int mf = 0; mf < 4; ++mf)                           \
    _Pragma("unroll") for (int ks = 0; ks < 2; ++ks)                           \
        aR[mf][ks] = *(const bf16x8*)((Ac) + ((subA + mf) * 2 + ks) * 1024 + inner); \
    if (doP) stage_half(A, lda, m0, kA, (An), w, lane);                        \
    __builtin_amdgcn_s_barrier();                                              \
    __builtin_amdgcn_s_setprio(1);                                             \
    _Pragma("unroll") for (int mf = 0; mf < 4; ++mf)                           \
    _Pragma("unroll") for (int nf = 0; nf < 2; ++nf)                           \
    _Pragma("unroll") for (int ks = 0; ks < 2; ++ks)                           \
        acc[mf][nf] = MFMA16(aR[mf][ks], CLo[nf][ks], acc[mf][nf]);            \
    __builtin_amdgcn_s_setprio(0);                                             \
    __builtin_amdgcn_s_barrier();                                              \
    FENCE();                                                                   \
    /* p1: issue next-tile B-lo loads; MFMA q(lo,hi) */                        \
    if (doP) {                                                                 \
        _Pragma("unroll") for (int nf = 0; nf < 2; ++nf)                       \
        _Pragma("unroll") for (int ks = 0; ks < 2; ++ks)                       \
            NLo[nf][ks] = *(const bf16x8*)(bp + bo + nf * nstep + ks * 32);    \
    }                                                                          \
    __builtin_amdgcn_s_barrier();                                              \
    __builtin_amdgcn_s_setprio(1);                                             \
    _Pragma("unroll") for (int mf = 0; mf < 4; ++mf)                           \
    _Pragma("unroll") for (int nf = 0; nf < 2; ++nf)                           \
    _Pragma("unroll") for (int ks = 0; ks < 2; ++ks)                           \
        acc[mf][2 + nf] = MFMA16(aR[mf][ks], CHi[nf][ks], acc[mf][2 + nf]);    \
    __builtin_amdgcn_s_setprio(0);                                             \
    __builtin_amdgcn_s_barrier();                                              \
    FENCE();                                                                   \
    /* p2: aR(wave m-hi) + stage A[t+1]h1; MFMA q(hi,lo) */                    \
    _Pragma("unroll") for (int mf = 0; mf < 4; ++mf)                           \
    _Pragma("unroll") for (int ks = 0; ks < 2; ++ks)                           \
        aR[mf][ks] = *(const bf16x8*)((Ac) + ((subA + 4 + mf) * 2 + ks) * 1024 + inner); \
    if (doP) stage_half(A, lda, m0 + 128, kA, (An) + 16384, w, lane);          \
    __builtin_amdgcn_s_barrier();                                              \
    __builtin_amdgcn_s_setprio(1);                                             \
    _Pragma("unroll") for (int mf = 0; mf < 4; ++mf)                           \
    _Pragma("unroll") for (int nf = 0; nf < 2; ++nf)                           \
    _Pragma("unroll") for (int ks = 0; ks < 2; ++ks)                           \
        acc[4 + mf][nf] = MFMA16(aR[mf][ks], CLo[nf][ks], acc[4 + mf][nf]);    \
    __builtin_amdgcn_s_setprio(0);                                             \
    __builtin_amdgcn_s_barrier();                                              \
    FENCE();                                                                   \
    /* p3: issue next-tile B-hi loads; MFMA q(hi,hi); counted vmcnt */         \
    if (doP) {                                                                 \
        _Pragma("unroll") for (int nf = 0; nf < 2; ++nf)                       \
        _Pragma("unroll") for (int ks = 0; ks < 2; ++ks)                       \
            NHi[nf][ks] = *(const bf16x8*)(bp + bo + (2 + nf) * nstep + ks * 32); \
    }                                                                          \
    __builtin_amdgcn_s_barrier();                                              \
    __builtin_amdgcn_s_setprio(1);                                             \
    _Pragma("unroll") for (int mf = 0; mf < 4; ++mf)                           \
    _Pragma("unroll") for (int nf = 0; nf < 2; ++nf)                           \
    _Pragma("unroll") for (int ks = 0; ks < 2; ++ks)                           \
        acc[4 + mf][2 + nf] = MFMA16(aR[mf][ks], CHi[nf][ks], acc[4 + mf][2 + nf]); \
    __builtin_amdgcn_s_setprio(0);                                             \
    if (doP) { asm volatile("s_waitcnt vmcnt(4)" ::: "memory"); }              \
    else     { asm volatile("s_waitcnt vmcnt(0)" ::: "memory"); }              \
    __builtin_amdgcn_s_barrier();                                              \
    FENCE();                                                                   \
}

__device__ __forceinline__ void gemm256_bd(
    const bf16* __restrict__ A, long lda,
    const bf16* __restrict__ Bt, long ldb,
    long m0, long n0, int NT, char* lds, f32x4 (&acc)[8][4])
{
    const int tid = threadIdx.x, lane = tid & 63, w = tid >> 6;
    const int lr = lane & 15, lkg = lane >> 4;
    const int subA = (w >> 2) * 8;
    const int inner = lr * 64 + (((lkg * 8) ^ ((lr >> 3) << 4)) << 1);

    char* A0b = lds;             // A tile dbuf: 2 x 32 KB
    char* A1b = lds + 32768;

    const bf16* bp = Bt + (n0 + (long)(w & 3) * 64 + lr) * ldb + lkg * 8;
    const long nstep = 16 * ldb;

    // prologue: A[0] both halves + B[0] lo/hi into S0/S1
    stage_half(A, lda, m0,       0, A0b,         w, lane);
    stage_half(A, lda, m0 + 128, 0, A0b + 16384, w, lane);
    bf16x8 bS0[2][2], bS1[2][2], bS2[2][2], bS3[2][2];
#pragma unroll
    for (int nf = 0; nf < 2; ++nf)
#pragma unroll
        for (int ks = 0; ks < 2; ++ks) {
            bS0[nf][ks] = *(const bf16x8*)(bp + nf * nstep + ks * 32);
            bS1[nf][ks] = *(const bf16x8*)(bp + (2 + nf) * nstep + ks * 32);
        }
    asm volatile("s_waitcnt vmcnt(0)" ::: "memory");
    __builtin_amdgcn_s_barrier();
    FENCE();

    bf16x8 aR[4][2];
    for (int t = 0; t < NT; t += 2) {
        QK_TILE(t,     A0b, A1b, bS0, bS1, bS2, bS3);
        QK_TILE(t + 1, A1b, A0b, bS2, bS3, bS0, bS1);
    }
}

// ===========================================================================
// 128x256 4-phase core (8 waves as 2M x 4N, 96 KB LDS) — pv & proj V
// ===========================================================================
__device__ __forceinline__ void gemm_h_core(
    const bf16* __restrict__ A, long lda,
    const bf16* __restrict__ Bt, long ldb,
    long m0, long n0, int NT, char* lds, f32x4 (&acc)[4][4])
{
    const int tid = threadIdx.x, lane = tid & 63, w = tid >> 6;
    const int lr = lane & 15, lkg = lane >> 4;
    const int subA = (w >> 2) * 4;
    const int subB = (w & 3) * 4;
    const int inner = lr * 64 + (((lkg * 8) ^ ((lr >> 3) << 4)) << 1);

    char* A0b = lds;
    char* B0b = lds + 16384;
    char* A1b = lds + 49152;
    char* B1b = lds + 65536;

    stage_half(A,  lda, m0,        0, A0b,          w, lane);
    stage_half(Bt, ldb, n0,        0, B0b,          w, lane);
    stage_half(Bt, ldb, n0 + 128,  0, B0b + 16384,  w, lane);
    stage_half(Bt, ldb, n0,       64, B1b,          w, lane);
    stage_half(Bt, ldb, n0 + 128, 64, B1b + 16384,  w, lane);
    asm volatile("s_waitcnt vmcnt(0)" ::: "memory");
    __builtin_amdgcn_s_barrier();
    FENCE();

    bf16x8 aR[2][2], bR[4][2];

    for (int t = 0; t < NT; ++t) {
        char* Ac = (t & 1) ? A1b : A0b;
        char* Bc = (t & 1) ? B1b : B0b;
        char* An = (t & 1) ? A0b : A1b;
        const long kA = (long)(t + 1) * 64;
        const long kB = (long)(t + 2) * 64;
        const bool doA = (t + 1 < NT), doB = (t + 2 < NT);

        // p0
#pragma unroll
        for (int mf = 0; mf < 2; ++mf)
#pragma unroll
            for (int ks = 0; ks < 2; ++ks)
                aR[mf][ks] = *(const bf16x8*)(Ac + ((subA + mf) * 2 + ks) * 1024 + inner);
#pragma unroll
        for (int nf = 0; nf < 2; ++nf)
#pragma unroll
            for (int ks = 0; ks < 2; ++ks)
                bR[nf][ks] = *(const bf16x8*)(Bc + ((subB + nf) * 2 + ks) * 1024 + inner);
        if (doA) stage_half(A, lda, m0, kA, An, w, lane);
        __builtin_amdgcn_s_barrier();
        __builtin_amdgcn_s_setprio(1);
#pragma unroll
        for (int mf = 0; mf < 2; ++mf)
#pragma unroll
            for (int nf = 0; nf < 2; ++nf)
#pragma unroll
                for (int ks = 0; ks < 2; ++ks)
                    acc[mf][nf] = MFMA16(aR[mf][ks], bR[nf][ks], acc[mf][nf]);
        __builtin_amdgcn_s_setprio(0);
        __builtin_amdgcn_s_barrier();
        FENCE();

        // p1
#pragma unroll
        for (int nf = 0; nf < 2; ++nf)
#pragma unroll
            for (int ks = 0; ks < 2; ++ks)
                bR[2 + nf][ks] = *(const bf16x8*)(Bc + ((subB + 2 + nf) * 2 + ks) * 1024 + inner);
        __builtin_amdgcn_s_barrier();
        __builtin_amdgcn_s_setprio(1);
#pragma unroll
        for (int mf = 0; mf < 2; ++mf)
#pragma unroll
            for (int nf = 0; nf < 2; ++nf)
#pragma unroll
                for (int ks = 0; ks < 2; ++ks)
                    acc[mf][2 + nf] = MFMA16(aR[mf][ks], bR[2 + nf][ks], acc[mf][2 + nf]);
        __builtin_amdgcn_s_setprio(0);
        __builtin_amdgcn_s_barrier();
        FENCE();

        // p2
#pragma unroll
        for (int mf = 0; mf < 2; ++mf)
#pragma unroll
            for (int ks = 0; ks < 2; ++ks)
                aR[mf][ks] = *(const bf16x8*)(Ac + ((subA + 2 + mf) * 2 + ks) * 1024 + inner);
        if (doB) {
            stage_half(Bt, ldb, n0,       kB, Bc,         w, lane);
            stage_half(Bt, ldb, n0 + 128, kB, Bc + 16384, w, lane);
        }
        __builtin_amdgcn_s_barrier();
        __builtin_amdgcn_s_setprio(1);
#pragma unroll
        for (int mf = 0; mf < 2; ++mf)
#pragma unroll
            for (int nf = 0; nf < 2; ++nf)
#pragma unroll
                for (int ks = 0; ks < 2; ++ks)
                    acc[2 + mf][nf] = MFMA16(aR[mf][ks], bR[nf][ks], acc[2 + mf][nf]);
        __builtin_amdgcn_s_setprio(0);
        __builtin_amdgcn_s_barrier();
        FENCE();

        // p3
        if (doB) {
            asm volatile("s_waitcnt vmcnt(4)" ::: "memory");
        } else {
            asm volatile("s_waitcnt vmcnt(0)" ::: "memory");
        }
        __builtin_amdgcn_s_barrier();
        __builtin_amdgcn_s_setprio(1);
#pragma unroll
        for (int mf = 0; mf < 2; ++mf)
#pragma unroll
            for (int nf = 0; nf < 2; ++nf)
#pragma unroll
                for (int ks = 0; ks < 2; ++ks)
                    acc[2 + mf][2 + nf] = MFMA16(aR[mf][ks], bR[2 + nf][ks], acc[2 + mf][2 + nf]);
        __builtin_amdgcn_s_setprio(0);
        __builtin_amdgcn_s_barrier();
        FENCE();
    }
}

// ---------------------------------------------------------------------------
// merged convert kernel: X->Xb, W->Wt (transposed), and zero the l buffer
// ---------------------------------------------------------------------------
__global__ __launch_bounds__(256) void conv_kernel(
    const float* __restrict__ X, const float* __restrict__ W,
    bf16* __restrict__ Xb, bf16* __restrict__ Wt, float* __restrict__ lbuf)
{
    __shared__ bf16 T[64][66];
    const int bid = blockIdx.x;
    if (bid < 4096) {
        const long i = ((long)bid * 256 + threadIdx.x) * 8;
        float4 a = *(const float4*)(X + i);
        float4 b = *(const float4*)(X + i + 4);
        bf16x8 o;
        o[0] = (bf16)a.x; o[1] = (bf16)a.y; o[2] = (bf16)a.z; o[3] = (bf16)a.w;
        o[4] = (bf16)b.x; o[5] = (bf16)b.y; o[6] = (bf16)b.z; o[7] = (bf16)b.w;
        *(bf16x8*)(Xb + i) = o;
    } else if (bid < 4096 + 768) {
        const int b2 = bid - 4096;
        const int n0 = (b2 % 48) * 64, k0 = (b2 / 48) * 64;
        const int r = threadIdx.x >> 2, s = threadIdx.x & 3;
        const float* wp = W + (size_t)(k0 + r) * H3 + n0 + s * 16;
#pragma unroll
        for (int q = 0; q < 4; ++q) {
            float4 a = *(const float4*)(wp + q * 4);
            T[r][s * 16 + q * 4 + 0] = (bf16)a.x;
            T[r][s * 16 + q * 4 + 1] = (bf16)a.y;
            T[r][s * 16 + q * 4 + 2] = (bf16)a.z;
            T[r][s * 16 + q * 4 + 3] = (bf16)a.w;
        }
        __syncthreads();
        bf16x8 o0, o1;
#pragma unroll
        for (int i = 0; i < 8; ++i) o0[i] = T[s * 16 + i][r];
#pragma unroll
        for (int i = 0; i < 8; ++i) o1[i] = T[s * 16 + 8 + i][r];
        bf16* op = Wt + (size_t)(n0 + r) * HID + k0 + s * 16;
        *(bf16x8*)op       = o0;
        *(bf16x8*)(op + 8) = o1;
    } else {
        for (int i = threadIdx.x; i < MTOT; i += 256) lbuf[i] = 0.0f;
    }
}

// ---------------------------------------------------------------------------
// proj (mixed tiling, one launch, 512 WGs):
//   bids   0..255: Q+K as 256x256 tiles on gemm256_bd (bn = bid&7 XCD-locks
//                  each Wt n-panel to one XCD's L2)
//   bids 256..511: V  as 128x256 tiles on gemm_h_core
// ---------------------------------------------------------------------------
__global__ __launch_bounds__(512, 2) void proj_mixed(
    const bf16* __restrict__ Xb, const bf16* __restrict__ Wt,
    const float* __restrict__ bias,
    bf16* __restrict__ Qb, bf16* __restrict__ Kb, bf16* __restrict__ Vt)
{
    __shared__ __attribute__((aligned(16))) char lds[135168];
    const int bid = blockIdx.x;
    const int tid = threadIdx.x, lane = tid & 63, w = tid >> 6;
    const int lr = lane & 15, lkg = lane >> 4;

    if (bid < 256) {
        // ---- Q/K: 256x256 tiles, B-direct core
        const int bn = bid & 7;             // n-panel pinned per XCD
        const int bm = bid >> 3;            // 0..31
        f32x4 acc[8][4] = {};
        gemm256_bd(Xb, HID, Wt, HID, (long)bm * 256, (long)bn * 256, 16, lds, acc);

        const int wmL = (w >> 2) * 128;
        const int wnL = (w & 3) * 64;
        const int seg = bn >> 2;            // 0=Q, 1=K

        __syncthreads();
        bf16* sm_ = (bf16*)lds;
        const float qs = (seg == 0) ? 0.03125f : 1.0f;
#pragma unroll
        for (int nf = 0; nf < 4; ++nf) {
            const int nl = wnL + nf * 16 + lr;
            const float bv = bias[bn * 256 + nl];
#pragma unroll
            for (int mf = 0; mf < 8; ++mf) {
                const int ml = wmL + mf * 16 + lkg * 4;
#pragma unroll
                for (int j = 0; j < 4; ++j)
                    sm_[(ml + j) * 264 + nl] = (bf16)((acc[mf][nf][j] + bv) * qs);
            }
        }
        __syncthreads();
        bf16* dst = (seg == 0) ? Qb : Kb;
        const long rowbase = (long)bm * 256;
        const long colbase = (long)(bn & 3) * 256;
#pragma unroll
        for (int it = 0; it < 16; ++it) {
            const int ml = (tid >> 5) + it * 16;
            const int nc = (tid & 31) * 8;
            bf16x8 vv = *(const bf16x8*)&sm_[ml * 264 + nc];
            *(bf16x8*)&dst[(rowbase + ml) * HID + colbase + nc] = vv;
        }
    } else {
        // ---- V: 128x256 tiles (output transposed to Vt [b][h][s])
        const int b2 = bid - 256;
        const int x = b2 & 7, q2 = b2 >> 3;
        const int vm = x * 8 + (q2 & 7);    // 0..63
        const int vn = q2 >> 3;             // 0..3
        f32x4 acc[4][4] = {};
        gemm_h_core(Xb, HID, Wt, HID, (long)vm * 128, 2048 + (long)vn * 256,
                    16, lds, acc);

        const int wmL = (w >> 2) * 64;
        const int wnL = (w & 3) * 64;

        __syncthreads();
        bf16* sm_ = (bf16*)lds;            // [256][136]
#pragma unroll
        for (int nf = 0; nf < 4; ++nf) {
            const int nl = wnL + nf * 16 + lr;
            const float bv = bias[2048 + vn * 256 + nl];
#pragma unroll
            for (int mf = 0; mf < 4; ++mf) {
                const int ml = wmL + mf * 16 + lkg * 4;
                bf16x4 pk;
#pragma unroll
                for (int j = 0; j < 4; ++j) pk[j] = (bf16)(acc[mf][nf][j] + bv);
                *(bf16x4*)&sm_[nl * 136 + ml] = pk;
            }
        }
        __syncthreads();
        const int  bb = vm >> 4;
        const long s0 = (long)(vm & 15) * 128;
        const long h0 = (long)vn * 256;
#pragma unroll
        for (int it = 0; it < 8; ++it) {
            const int nl = (tid >> 4) + it * 32;
            const int mc = (tid & 15) * 8;
            bf16x8 vv = *(const bf16x8*)&sm_[nl * 136 + mc];
            *(bf16x8*)&Vt[((long)(bb << 10) + h0 + nl) * SEQ + s0 + mc] = vv;
        }
    }
}

// ---------------------------------------------------------------------------
// qk + fused exp/mask + row-sum on the B-direct core.
// grid (64,1,nbg); bn = x&7 pins each Kb n-panel to one XCD.
// ---------------------------------------------------------------------------
__global__ __launch_bounds__(512, 2) void qk_gemm2(
    const bf16* __restrict__ Qb, const bf16* __restrict__ Kb,
    bf16* __restrict__ Pb, float* __restrict__ lbuf,
    const float* __restrict__ mask, int b_base)
{
    __shared__ __attribute__((aligned(16))) char lds[135168];
    __shared__ float lsum[2][128][4];
    const int z = blockIdx.z, b = b_base + z;
    const int bn = (int)blockIdx.x & 7;
    const int bm = (int)blockIdx.x >> 3;

    f32x4 acc[8][4] = {};
    gemm256_bd(Qb + (size_t)b * SEQ * HID, HID,
               Kb + (size_t)b * SEQ * HID, HID,
               (long)bm * 256, (long)bn * 256, 16, lds, acc);

    const int tid = threadIdx.x, lane = tid & 63, w = tid >> 6;
    const int lr = lane & 15, lkg = lane >> 4;
    const int mh = w >> 2;
    const int nw = w & 3;

    __syncthreads();
    bf16* smP = (bf16*)lds;

    float mterm[4];
#pragma unroll
    for (int nf = 0; nf < 4; ++nf) {
        const int col = bn * 256 + nw * 64 + nf * 16 + lr;
        mterm[nf] = (1.0f - mask[(size_t)b * SEQ + col]) * -10000.0f;
    }

#pragma unroll
    for (int mf = 0; mf < 8; ++mf) {
#pragma unroll
        for (int j = 0; j < 4; ++j) {
            const int rloc = mf * 16 + lkg * 4 + j;
            float rs = 0.0f;
#pragma unroll
            for (int nf = 0; nf < 4; ++nf) {
                const float e = __expf(acc[mf][nf][j] + mterm[nf]);
                smP[(mh * 128 + rloc) * 264 + nw * 64 + nf * 16 + lr] = (bf16)e;
                rs += e;
            }
            rs += __shfl_xor(rs, 1);
            rs += __shfl_xor(rs, 2);
            rs += __shfl_xor(rs, 4);
            rs += __shfl_xor(rs, 8);
            if (lr == 0) lsum[mh][rloc][nw] = rs;
        }
    }
    __syncthreads();

    bf16* P = Pb + (size_t)z * SEQ * SEQ;
    const long rowbase = (long)bm * 256;
    const long colbase = (long)bn * 256;
#pragma unroll
    for (int it = 0; it < 16; ++it) {
        const int ml = (tid >> 5) + it * 16;
        const int nc = (tid & 31) * 8;
        bf16x8 vv = *(const bf16x8*)&smP[ml * 264 + nc];
        *(bf16x8*)&P[(rowbase + ml) * SEQ + colbase + nc] = vv;
    }

    if (tid < 256) {
        const int half = tid >> 7, r128 = tid & 127;
        const float s4 = lsum[half][r128][0] + lsum[half][r128][1]
                       + lsum[half][r128][2] + lsum[half][r128][3];
        atomicAdd(&lbuf[(size_t)b * SEQ + rowbase + tid], s4);
    }
}

// ---------------------------------------------------------------------------
// out = (P' @ Vt^T) / l  (per batch); 128x256 tiles -> 256 WGs exact
// ---------------------------------------------------------------------------
__global__ __launch_bounds__(512, 2) void pv_gemm2(
    const bf16* __restrict__ Pb, const bf16* __restrict__ Vt,
    const float* __restrict__ lbuf, float* __restrict__ out, int b_base)
{
    __shared__ __attribute__((aligned(16))) char lds[98304];
    const int z = blockIdx.z, b = b_base + z;

    f32x4 acc[4][4] = {};
    gemm_h_core(Pb + (size_t)z * SEQ * SEQ, SEQ,
                Vt + (size_t)b * HID * SEQ, SEQ,
                (long)blockIdx.x * 128, (long)blockIdx.y * 256, 32, lds, acc);

    const int tid = threadIdx.x, lane = tid & 63, w = tid >> 6;
    const int lr = lane & 15, lkg = lane >> 4;
    const int m0i = (int)blockIdx.x * 128 + (w >> 2) * 64;
    const int n0i = (int)blockIdx.y * 256 + (w & 3) * 64;
    float* C = out + (size_t)b * SEQ * HID;
#pragma unroll
    for (int mf = 0; mf < 4; ++mf)
#pragma unroll
        for (int j = 0; j < 4; ++j) {
            const int row = m0i + mf * 16 + lkg * 4 + j;
            const float inv = 1.0f / lbuf[(size_t)b * SEQ + row];
#pragma unroll
            for (int nf = 0; nf < 4; ++nf)
                C[(size_t)row * HID + n0i + nf * 16 + lr] = acc[mf][nf][j] * inv;
        }
}

// ---------------------------------------------------------------------------
extern "C" void kernel_launch(void* const* d_in, const int* in_sizes, int n_in,
                              void* d_out, int out_size, void* d_ws, size_t ws_size,
                              hipStream_t stream)
{
    const float* X    = (const float*)d_in[0];
    const float* mask = (const float*)d_in[1];
    const float* W    = (const float*)d_in[2];
    const float* bias = (const float*)d_in[3];
    float* out = (float*)d_out;

    char* ws = (char*)d_ws;
    const size_t MB = 1024 * 1024;
    bf16*  Qb   = (bf16*)ws;                  // 16 MB
    bf16*  Kb   = (bf16*)(ws + 16 * MB);      // 16 MB
    bf16*  Vt   = (bf16*)(ws + 32 * MB);      // 16 MB
    float* lbuf = (float*)(ws + 48 * MB);     // 32 KB
    bf16*  Xb   = (bf16*)(ws + 49 * MB);      // 16 MB (U region)
    bf16*  Wt   = (bf16*)(ws + 65 * MB);      // 6 MB  (U region)
    bf16*  Pb   = (bf16*)(ws + 49 * MB);      // nbg*8 MB (overlays U)

    int nbg;
    if      (ws_size >= 81 * MB) nbg = 4;
    else if (ws_size >= 65 * MB) nbg = 2;
    else                         nbg = 1;

    conv_kernel<<<4096 + 768 + 1, 256, 0, stream>>>(X, W, Xb, Wt, lbuf);
    proj_mixed<<<512, 512, 0, stream>>>(Xb, Wt, bias, Qb, Kb, Vt);

    for (int g = 0; g < NB / nbg; ++g) {
        const int b0 = g * nbg;
        qk_gemm2<<<dim3(64, 1, nbg), 512, 0, stream>>>(Qb, Kb, Pb, lbuf, mask, b0);
        pv_gemm2<<<dim3(16, 4, nbg), 512, 0, stream>>>(Pb, Vt, lbuf, out, b0);
    }
}

// Round 11
// 152.961 us; speedup vs baseline: 1.2044x; 1.2044x over previous
//
#include <hip/hip_runtime.h>
#include <hip/hip_bf16.h>

#define HID   1024
#define H3    3072
#define SEQ   2048
#define NB    4
#define MTOT  8192   // NB*SEQ

typedef __bf16 bf16;
typedef bf16  bf16x4 __attribute__((ext_vector_type(4)));
typedef bf16  bf16x8 __attribute__((ext_vector_type(8)));
typedef float f32x4  __attribute__((ext_vector_type(4)));

#define MFMA16(a, b, c) __builtin_amdgcn_mfma_f32_16x16x32_bf16((a), (b), (c), 0, 0, 0)

#define GLOAD_LDS16(gp, lp)                                                     \
    __builtin_amdgcn_global_load_lds(                                           \
        (const __attribute__((address_space(1))) void*)(gp),                    \
        (__attribute__((address_space(3))) void*)(lp), 16, 0, 0)

#define FENCE() asm volatile("" ::: "memory")

// ===========================================================================
// Common staging: 128 rows x 64 cols of bf16 as 16 subtiles (16x32, 1024 B)
// with involutive XOR swizzle (pre-swizzled global source, linear LDS dest).
// ===========================================================================
__device__ __forceinline__ void stage_half(
    const bf16* __restrict__ G, long ld, long row0, long col0,
    char* dstbase, int w, int lane)
{
    const int r  = lane >> 2;                                   // 0..15
    const int c0 = ((lane & 3) * 8) ^ (((lane >> 5) & 1) << 4); // pre-swizzled col
#pragma unroll
    for (int l = 0; l < 2; ++l) {
        const int sh = l * 8 + w;                               // subtile 0..15
        const bf16* src = G + (row0 + (long)((sh >> 1) * 16 + r)) * ld
                            + col0 + ((sh & 1) * 32 + c0);
        GLOAD_LDS16(src, dstbase + sh * 1024);
    }
}

// ===========================================================================
// 256x256 8-phase core (BK=64, 8 waves, 128 KB LDS) — qk & proj Q/K tiles
// ===========================================================================
__device__ __forceinline__ void gemm256_core(
    const bf16* __restrict__ A, long lda,
    const bf16* __restrict__ Bt, long ldb,
    long m0, long n0, int NT, char* lds, f32x4 (&acc)[8][4])
{
    const int tid = threadIdx.x, lane = tid & 63, w = tid >> 6;
    const int lr = lane & 15, lkg = lane >> 4;
    const int subA = (w >> 2) * 8;
    const int subB = (w & 3) * 4;
    const int inner = lr * 64 + (((lkg * 8) ^ ((lr >> 3) << 4)) << 1);

    char* A0b = lds;
    char* B0b = lds + 32768;
    char* A1b = lds + 65536;
    char* B1b = lds + 98304;

    stage_half(A,  lda, m0,        0, A0b,          w, lane);
    stage_half(A,  lda, m0 + 128,  0, A0b + 16384,  w, lane);
    stage_half(Bt, ldb, n0,        0, B0b,          w, lane);
    stage_half(Bt, ldb, n0 + 128,  0, B0b + 16384,  w, lane);
    stage_half(Bt, ldb, n0,       64, B1b,          w, lane);
    stage_half(Bt, ldb, n0 + 128, 64, B1b + 16384,  w, lane);
    asm volatile("s_waitcnt vmcnt(0)" ::: "memory");
    __builtin_amdgcn_s_barrier();
    FENCE();

    bf16x8 aR[4][2], bR[4][2];

    for (int t = 0; t < NT; ++t) {
        char* Ac = (t & 1) ? A1b : A0b;
        char* Bc = (t & 1) ? B1b : B0b;
        char* An = (t & 1) ? A0b : A1b;
        const long kA = (long)(t + 1) * 64;
        const long kB = (long)(t + 2) * 64;
        const bool doA = (t + 1 < NT), doB = (t + 2 < NT);

        // phase 0
#pragma unroll
        for (int mf = 0; mf < 4; ++mf)
#pragma unroll
            for (int ks = 0; ks < 2; ++ks)
                aR[mf][ks] = *(const bf16x8*)(Ac + ((subA + mf) * 2 + ks) * 1024 + inner);
#pragma unroll
        for (int nf = 0; nf < 2; ++nf)
#pragma unroll
            for (int ks = 0; ks < 2; ++ks)
                bR[nf][ks] = *(const bf16x8*)(Bc + ((subB + nf) * 2 + ks) * 1024 + inner);
        if (doA) stage_half(A, lda, m0, kA, An, w, lane);
        __builtin_amdgcn_s_barrier();
        __builtin_amdgcn_s_setprio(1);
#pragma unroll
        for (int mf = 0; mf < 4; ++mf)
#pragma unroll
            for (int nf = 0; nf < 2; ++nf)
#pragma unroll
                for (int ks = 0; ks < 2; ++ks)
                    acc[mf][nf] = MFMA16(aR[mf][ks], bR[nf][ks], acc[mf][nf]);
        __builtin_amdgcn_s_setprio(0);
        __builtin_amdgcn_s_barrier();
        FENCE();

        // phase 1
#pragma unroll
        for (int nf = 0; nf < 2; ++nf)
#pragma unroll
            for (int ks = 0; ks < 2; ++ks)
                bR[2 + nf][ks] = *(const bf16x8*)(Bc + ((subB + 2 + nf) * 2 + ks) * 1024 + inner);
        if (doA) stage_half(A, lda, m0 + 128, kA, An + 16384, w, lane);
        __builtin_amdgcn_s_barrier();
        __builtin_amdgcn_s_setprio(1);
#pragma unroll
        for (int mf = 0; mf < 4; ++mf)
#pragma unroll
            for (int nf = 0; nf < 2; ++nf)
#pragma unroll
                for (int ks = 0; ks < 2; ++ks)
                    acc[mf][2 + nf] = MFMA16(aR[mf][ks], bR[2 + nf][ks], acc[mf][2 + nf]);
        __builtin_amdgcn_s_setprio(0);
        __builtin_amdgcn_s_barrier();
        FENCE();

        // phase 2
#pragma unroll
        for (int mf = 0; mf < 4; ++mf)
#pragma unroll
            for (int ks = 0; ks < 2; ++ks)
                aR[mf][ks] = *(const bf16x8*)(Ac + ((subA + 4 + mf) * 2 + ks) * 1024 + inner);
        if (doB) stage_half(Bt, ldb, n0, kB, Bc, w, lane);
        __builtin_amdgcn_s_barrier();
        __builtin_amdgcn_s_setprio(1);
#pragma unroll
        for (int mf = 0; mf < 4; ++mf)
#pragma unroll
            for (int nf = 0; nf < 2; ++nf)
#pragma unroll
                for (int ks = 0; ks < 2; ++ks)
                    acc[4 + mf][nf] = MFMA16(aR[mf][ks], bR[nf][ks], acc[4 + mf][nf]);
        __builtin_amdgcn_s_setprio(0);
        __builtin_amdgcn_s_barrier();
        FENCE();

        // phase 3
        if (doB) {
            stage_half(Bt, ldb, n0 + 128, kB, Bc + 16384, w, lane);
            asm volatile("s_waitcnt vmcnt(4)" ::: "memory");
        } else {
            asm volatile("s_waitcnt vmcnt(0)" ::: "memory");
        }
        __builtin_amdgcn_s_barrier();
        __builtin_amdgcn_s_setprio(1);
#pragma unroll
        for (int mf = 0; mf < 4; ++mf)
#pragma unroll
            for (int nf = 0; nf < 2; ++nf)
#pragma unroll
                for (int ks = 0; ks < 2; ++ks)
                    acc[4 + mf][2 + nf] = MFMA16(aR[mf][ks], bR[2 + nf][ks], acc[4 + mf][2 + nf]);
        __builtin_amdgcn_s_setprio(0);
        __builtin_amdgcn_s_barrier();
        FENCE();
    }
}

// ===========================================================================
// 128x256 4-phase core (BK=64, 8 waves as 2M x 4N, 96 KB LDS) — pv & proj V
// ===========================================================================
__device__ __forceinline__ void gemm_h_core(
    const bf16* __restrict__ A, long lda,
    const bf16* __restrict__ Bt, long ldb,
    long m0, long n0, int NT, char* lds, f32x4 (&acc)[4][4])
{
    const int tid = threadIdx.x, lane = tid & 63, w = tid >> 6;
    const int lr = lane & 15, lkg = lane >> 4;
    const int subA = (w >> 2) * 4;
    const int subB = (w & 3) * 4;
    const int inner = lr * 64 + (((lkg * 8) ^ ((lr >> 3) << 4)) << 1);

    char* A0b = lds;
    char* B0b = lds + 16384;
    char* A1b = lds + 49152;
    char* B1b = lds + 65536;

    stage_half(A,  lda, m0,        0, A0b,          w, lane);
    stage_half(Bt, ldb, n0,        0, B0b,          w, lane);
    stage_half(Bt, ldb, n0 + 128,  0, B0b + 16384,  w, lane);
    stage_half(Bt, ldb, n0,       64, B1b,          w, lane);
    stage_half(Bt, ldb, n0 + 128, 64, B1b + 16384,  w, lane);
    asm volatile("s_waitcnt vmcnt(0)" ::: "memory");
    __builtin_amdgcn_s_barrier();
    FENCE();

    bf16x8 aR[2][2], bR[4][2];

    for (int t = 0; t < NT; ++t) {
        char* Ac = (t & 1) ? A1b : A0b;
        char* Bc = (t & 1) ? B1b : B0b;
        char* An = (t & 1) ? A0b : A1b;
        const long kA = (long)(t + 1) * 64;
        const long kB = (long)(t + 2) * 64;
        const bool doA = (t + 1 < NT), doB = (t + 2 < NT);

        // p0
#pragma unroll
        for (int mf = 0; mf < 2; ++mf)
#pragma unroll
            for (int ks = 0; ks < 2; ++ks)
                aR[mf][ks] = *(const bf16x8*)(Ac + ((subA + mf) * 2 + ks) * 1024 + inner);
#pragma unroll
        for (int nf = 0; nf < 2; ++nf)
#pragma unroll
            for (int ks = 0; ks < 2; ++ks)
                bR[nf][ks] = *(const bf16x8*)(Bc + ((subB + nf) * 2 + ks) * 1024 + inner);
        if (doA) stage_half(A, lda, m0, kA, An, w, lane);
        __builtin_amdgcn_s_barrier();
        __builtin_amdgcn_s_setprio(1);
#pragma unroll
        for (int mf = 0; mf < 2; ++mf)
#pragma unroll
            for (int nf = 0; nf < 2; ++nf)
#pragma unroll
                for (int ks = 0; ks < 2; ++ks)
                    acc[mf][nf] = MFMA16(aR[mf][ks], bR[nf][ks], acc[mf][nf]);
        __builtin_amdgcn_s_setprio(0);
        __builtin_amdgcn_s_barrier();
        FENCE();

        // p1
#pragma unroll
        for (int nf = 0; nf < 2; ++nf)
#pragma unroll
            for (int ks = 0; ks < 2; ++ks)
                bR[2 + nf][ks] = *(const bf16x8*)(Bc + ((subB + 2 + nf) * 2 + ks) * 1024 + inner);
        __builtin_amdgcn_s_barrier();
        __builtin_amdgcn_s_setprio(1);
#pragma unroll
        for (int mf = 0; mf < 2; ++mf)
#pragma unroll
            for (int nf = 0; nf < 2; ++nf)
#pragma unroll
                for (int ks = 0; ks < 2; ++ks)
                    acc[mf][2 + nf] = MFMA16(aR[mf][ks], bR[2 + nf][ks], acc[mf][2 + nf]);
        __builtin_amdgcn_s_setprio(0);
        __builtin_amdgcn_s_barrier();
        FENCE();

        // p2
#pragma unroll
        for (int mf = 0; mf < 2; ++mf)
#pragma unroll
            for (int ks = 0; ks < 2; ++ks)
                aR[mf][ks] = *(const bf16x8*)(Ac + ((subA + 2 + mf) * 2 + ks) * 1024 + inner);
        if (doB) {
            stage_half(Bt, ldb, n0,       kB, Bc,         w, lane);
            stage_half(Bt, ldb, n0 + 128, kB, Bc + 16384, w, lane);
        }
        __builtin_amdgcn_s_barrier();
        __builtin_amdgcn_s_setprio(1);
#pragma unroll
        for (int mf = 0; mf < 2; ++mf)
#pragma unroll
            for (int nf = 0; nf < 2; ++nf)
#pragma unroll
                for (int ks = 0; ks < 2; ++ks)
                    acc[2 + mf][nf] = MFMA16(aR[mf][ks], bR[nf][ks], acc[2 + mf][nf]);
        __builtin_amdgcn_s_setprio(0);
        __builtin_amdgcn_s_barrier();
        FENCE();

        // p3
        if (doB) {
            asm volatile("s_waitcnt vmcnt(4)" ::: "memory");
        } else {
            asm volatile("s_waitcnt vmcnt(0)" ::: "memory");
        }
        __builtin_amdgcn_s_barrier();
        __builtin_amdgcn_s_setprio(1);
#pragma unroll
        for (int mf = 0; mf < 2; ++mf)
#pragma unroll
            for (int nf = 0; nf < 2; ++nf)
#pragma unroll
                for (int ks = 0; ks < 2; ++ks)
                    acc[2 + mf][2 + nf] = MFMA16(aR[mf][ks], bR[2 + nf][ks], acc[2 + mf][2 + nf]);
        __builtin_amdgcn_s_setprio(0);
        __builtin_amdgcn_s_barrier();
        FENCE();
    }
}

// ---------------------------------------------------------------------------
// merged convert kernel: X->Xb, W->Wt (transposed), and zero the l buffer
// ---------------------------------------------------------------------------
__global__ __launch_bounds__(256) void conv_kernel(
    const float* __restrict__ X, const float* __restrict__ W,
    bf16* __restrict__ Xb, bf16* __restrict__ Wt, float* __restrict__ lbuf)
{
    __shared__ bf16 T[64][66];
    const int bid = blockIdx.x;
    if (bid < 4096) {
        const long i = ((long)bid * 256 + threadIdx.x) * 8;
        float4 a = *(const float4*)(X + i);
        float4 b = *(const float4*)(X + i + 4);
        bf16x8 o;
        o[0] = (bf16)a.x; o[1] = (bf16)a.y; o[2] = (bf16)a.z; o[3] = (bf16)a.w;
        o[4] = (bf16)b.x; o[5] = (bf16)b.y; o[6] = (bf16)b.z; o[7] = (bf16)b.w;
        *(bf16x8*)(Xb + i) = o;
    } else if (bid < 4096 + 768) {
        const int b2 = bid - 4096;
        const int n0 = (b2 % 48) * 64, k0 = (b2 / 48) * 64;
        const int r = threadIdx.x >> 2, s = threadIdx.x & 3;
        const float* wp = W + (size_t)(k0 + r) * H3 + n0 + s * 16;
#pragma unroll
        for (int q = 0; q < 4; ++q) {
            float4 a = *(const float4*)(wp + q * 4);
            T[r][s * 16 + q * 4 + 0] = (bf16)a.x;
            T[r][s * 16 + q * 4 + 1] = (bf16)a.y;
            T[r][s * 16 + q * 4 + 2] = (bf16)a.z;
            T[r][s * 16 + q * 4 + 3] = (bf16)a.w;
        }
        __syncthreads();
        bf16x8 o0, o1;
#pragma unroll
        for (int i = 0; i < 8; ++i) o0[i] = T[s * 16 + i][r];
#pragma unroll
        for (int i = 0; i < 8; ++i) o1[i] = T[s * 16 + 8 + i][r];
        bf16* op = Wt + (size_t)(n0 + r) * HID + k0 + s * 16;
        *(bf16x8*)op       = o0;
        *(bf16x8*)(op + 8) = o1;
    } else {
        for (int i = threadIdx.x; i < MTOT; i += 256) lbuf[i] = 0.0f;
    }
}

// ---------------------------------------------------------------------------
// proj (mixed tiling, one launch, 512 WGs):
//   bids   0..255: Q+K as 256x256 tiles on gemm256_core (32m x 8n = 256 exact)
//   bids 256..511: V  as 128x256 tiles on gemm_h_core   (64m x 4n = 256 exact)
// ---------------------------------------------------------------------------
__global__ __launch_bounds__(512, 2) void proj_mixed(
    const bf16* __restrict__ Xb, const bf16* __restrict__ Wt,
    const float* __restrict__ bias,
    bf16* __restrict__ Qb, bf16* __restrict__ Kb, bf16* __restrict__ Vt)
{
    __shared__ __attribute__((aligned(16))) char lds[135168];
    const int bid = blockIdx.x;
    const int tid = threadIdx.x, lane = tid & 63, w = tid >> 6;
    const int lr = lane & 15, lkg = lane >> 4;

    if (bid < 256) {
        // ---- Q/K: 256x256 tiles
        const int x = bid & 7, q = bid >> 3;
        const int bm = x * 4 + (q & 3);     // 0..31
        const int bn = q >> 2;              // 0..7
        f32x4 acc[8][4] = {};
        gemm256_core(Xb, HID, Wt, HID, (long)bm * 256, (long)bn * 256, 16, lds, acc);

        const int wmL = (w >> 2) * 128;
        const int wnL = (w & 3) * 64;
        const int seg = bn >> 2;            // 0=Q, 1=K

        __syncthreads();
        bf16* sm_ = (bf16*)lds;
        const float qs = (seg == 0) ? 0.03125f : 1.0f;
#pragma unroll
        for (int nf = 0; nf < 4; ++nf) {
            const int nl = wnL + nf * 16 + lr;
            const float bv = bias[bn * 256 + nl];
#pragma unroll
            for (int mf = 0; mf < 8; ++mf) {
                const int ml = wmL + mf * 16 + lkg * 4;
#pragma unroll
                for (int j = 0; j < 4; ++j)
                    sm_[(ml + j) * 264 + nl] = (bf16)((acc[mf][nf][j] + bv) * qs);
            }
        }
        __syncthreads();
        bf16* dst = (seg == 0) ? Qb : Kb;
        const long rowbase = (long)bm * 256;
        const long colbase = (long)(bn & 3) * 256;
#pragma unroll
        for (int it = 0; it < 16; ++it) {
            const int ml = (tid >> 5) + it * 16;
            const int nc = (tid & 31) * 8;
            bf16x8 vv = *(const bf16x8*)&sm_[ml * 264 + nc];
            *(bf16x8*)&dst[(rowbase + ml) * HID + colbase + nc] = vv;
        }
    } else {
        // ---- V: 128x256 tiles (output transposed to Vt [b][h][s])
        const int b2 = bid - 256;
        const int x = b2 & 7, q2 = b2 >> 3;
        const int vm = x * 8 + (q2 & 7);    // 0..63  (128-row m tile)
        const int vn = q2 >> 3;             // 0..3   (256-col n tile)
        f32x4 acc[4][4] = {};
        gemm_h_core(Xb, HID, Wt, HID, (long)vm * 128, 2048 + (long)vn * 256,
                    16, lds, acc);

        const int wmL = (w >> 2) * 64;
        const int wnL = (w & 3) * 64;

        __syncthreads();
        bf16* sm_ = (bf16*)lds;            // [256][136]
#pragma unroll
        for (int nf = 0; nf < 4; ++nf) {
            const int nl = wnL + nf * 16 + lr;
            const float bv = bias[2048 + vn * 256 + nl];
#pragma unroll
            for (int mf = 0; mf < 4; ++mf) {
                const int ml = wmL + mf * 16 + lkg * 4;
                bf16x4 pk;
#pragma unroll
                for (int j = 0; j < 4; ++j) pk[j] = (bf16)(acc[mf][nf][j] + bv);
                *(bf16x4*)&sm_[nl * 136 + ml] = pk;
            }
        }
        __syncthreads();
        const int  bb = vm >> 4;                 // batch (16 m-tiles each)
        const long s0 = (long)(vm & 15) * 128;   // seq offset
        const long h0 = (long)vn * 256;          // head-dim offset
#pragma unroll
        for (int it = 0; it < 8; ++it) {
            const int nl = (tid >> 4) + it * 32;
            const int mc = (tid & 15) * 8;
            bf16x8 vv = *(const bf16x8*)&sm_[nl * 136 + mc];
            *(bf16x8*)&Vt[((long)(bb << 10) + h0 + nl) * SEQ + s0 + mc] = vv;
        }
    }
}

// ---------------------------------------------------------------------------
// qk + fused exp/mask + row-sum: P' = exp(Q@K^T + maskterm) as bf16,
// row sums atomically accumulated into lbuf. No max-subtraction needed.
// ---------------------------------------------------------------------------
__global__ __launch_bounds__(512, 2) void qk_gemm2(
    const bf16* __restrict__ Qb, const bf16* __restrict__ Kb,
    bf16* __restrict__ Pb, float* __restrict__ lbuf,
    const float* __restrict__ mask, int b_base)
{
    __shared__ __attribute__((aligned(16))) char lds[135168];
    __shared__ float lsum[2][128][4];
    const int z = blockIdx.z, b = b_base + z;

    f32x4 acc[8][4] = {};
    gemm256_core(Qb + (size_t)b * SEQ * HID, HID,
                 Kb + (size_t)b * SEQ * HID, HID,
                 (long)blockIdx.x * 256, (long)blockIdx.y * 256, 16, lds, acc);

    const int tid = threadIdx.x, lane = tid & 63, w = tid >> 6;
    const int lr = lane & 15, lkg = lane >> 4;
    const int mh = w >> 2;
    const int nw = w & 3;

    __syncthreads();
    bf16* smP = (bf16*)lds;

    float mterm[4];
#pragma unroll
    for (int nf = 0; nf < 4; ++nf) {
        const int col = (int)blockIdx.y * 256 + nw * 64 + nf * 16 + lr;
        mterm[nf] = (1.0f - mask[(size_t)b * SEQ + col]) * -10000.0f;
    }

#pragma unroll
    for (int mf = 0; mf < 8; ++mf) {
#pragma unroll
        for (int j = 0; j < 4; ++j) {
            const int rloc = mf * 16 + lkg * 4 + j;
            float rs = 0.0f;
#pragma unroll
            for (int nf = 0; nf < 4; ++nf) {
                const float e = __expf(acc[mf][nf][j] + mterm[nf]);
                smP[(mh * 128 + rloc) * 264 + nw * 64 + nf * 16 + lr] = (bf16)e;
                rs += e;
            }
            rs += __shfl_xor(rs, 1);
            rs += __shfl_xor(rs, 2);
            rs += __shfl_xor(rs, 4);
            rs += __shfl_xor(rs, 8);
            if (lr == 0) lsum[mh][rloc][nw] = rs;
        }
    }
    __syncthreads();

    bf16* P = Pb + (size_t)z * SEQ * SEQ;
    const long rowbase = (long)blockIdx.x * 256;
    const long colbase = (long)blockIdx.y * 256;
#pragma unroll
    for (int it = 0; it < 16; ++it) {
        const int ml = (tid >> 5) + it * 16;
        const int nc = (tid & 31) * 8;
        bf16x8 vv = *(const bf16x8*)&smP[ml * 264 + nc];
        *(bf16x8*)&P[(rowbase + ml) * SEQ + colbase + nc] = vv;
    }

    if (tid < 256) {
        const int half = tid >> 7, r128 = tid & 127;
        const float s4 = lsum[half][r128][0] + lsum[half][r128][1]
                       + lsum[half][r128][2] + lsum[half][r128][3];
        atomicAdd(&lbuf[(size_t)b * SEQ + rowbase + tid], s4);
    }
}

// ---------------------------------------------------------------------------
// out = (P' @ Vt^T) / l  (per batch); 128x256 tiles -> 256 WGs exact
// ---------------------------------------------------------------------------
__global__ __launch_bounds__(512, 2) void pv_gemm2(
    const bf16* __restrict__ Pb, const bf16* __restrict__ Vt,
    const float* __restrict__ lbuf, float* __restrict__ out, int b_base)
{
    __shared__ __attribute__((aligned(16))) char lds[98304];
    const int z = blockIdx.z, b = b_base + z;

    f32x4 acc[4][4] = {};
    gemm_h_core(Pb + (size_t)z * SEQ * SEQ, SEQ,
                Vt + (size_t)b * HID * SEQ, SEQ,
                (long)blockIdx.x * 128, (long)blockIdx.y * 256, 32, lds, acc);

    const int tid = threadIdx.x, lane = tid & 63, w = tid >> 6;
    const int lr = lane & 15, lkg = lane >> 4;
    const int m0i = (int)blockIdx.x * 128 + (w >> 2) * 64;
    const int n0i = (int)blockIdx.y * 256 + (w & 3) * 64;
    float* C = out + (size_t)b * SEQ * HID;
#pragma unroll
    for (int mf = 0; mf < 4; ++mf)
#pragma unroll
        for (int j = 0; j < 4; ++j) {
            const int row = m0i + mf * 16 + lkg * 4 + j;
            const float inv = 1.0f / lbuf[(size_t)b * SEQ + row];
#pragma unroll
            for (int nf = 0; nf < 4; ++nf)
                C[(size_t)row * HID + n0i + nf * 16 + lr] = acc[mf][nf][j] * inv;
        }
}

// ---------------------------------------------------------------------------
extern "C" void kernel_launch(void* const* d_in, const int* in_sizes, int n_in,
                              void* d_out, int out_size, void* d_ws, size_t ws_size,
                              hipStream_t stream)
{
    const float* X    = (const float*)d_in[0];
    const float* mask = (const float*)d_in[1];
    const float* W    = (const float*)d_in[2];
    const float* bias = (const float*)d_in[3];
    float* out = (float*)d_out;

    char* ws = (char*)d_ws;
    const size_t MB = 1024 * 1024;
    bf16*  Qb   = (bf16*)ws;                  // 16 MB
    bf16*  Kb   = (bf16*)(ws + 16 * MB);      // 16 MB
    bf16*  Vt   = (bf16*)(ws + 32 * MB);      // 16 MB
    float* lbuf = (float*)(ws + 48 * MB);     // 32 KB
    bf16*  Xb   = (bf16*)(ws + 49 * MB);      // 16 MB (U region)
    bf16*  Wt   = (bf16*)(ws + 65 * MB);      // 6 MB  (U region)
    bf16*  Pb   = (bf16*)(ws + 49 * MB);      // nbg*8 MB (overlays U)

    int nbg;
    if      (ws_size >= 81 * MB) nbg = 4;
    else if (ws_size >= 65 * MB) nbg = 2;
    else                         nbg = 1;

    conv_kernel<<<4096 + 768 + 1, 256, 0, stream>>>(X, W, Xb, Wt, lbuf);
    proj_mixed<<<512, 512, 0, stream>>>(Xb, Wt, bias, Qb, Kb, Vt);

    for (int g = 0; g < NB / nbg; ++g) {
        const int b0 = g * nbg;
        qk_gemm2<<<dim3(8, 8, nbg), 512, 0, stream>>>(Qb, Kb, Pb, lbuf, mask, b0);
        pv_gemm2<<<dim3(16, 4, nbg), 512, 0, stream>>>(Pb, Vt, lbuf, out, b0);
    }
}